// Round 3
// 73.256 us; speedup vs baseline: 1.1039x; 1.1039x over previous
//
#include <hip/hip_runtime.h>
#include <math.h>

#define BATCH 384
#define FEAT 256
#define GROUP 8
// ANNEAL = 0.01 -> 1/temp = 100

__device__ __forceinline__ float temp_sigmoid_from_diff(float diff) {
    // reference: exponent = clip(-t/temp, -50, 50); 1/(1+exp(exponent))
    float e = fminf(fmaxf(-100.0f * diff, -50.0f), 50.0f);
    return 1.0f / (1.0f + __expf(e));
}

// ---------------------------------------------------------------------------
// One block per query row i.
// Sim loop uses 16-lane clusters: each wave handles 4 gallery rows/iter,
// lanes (lane&15) hold contiguous 64B slices of one row -> every wave-level
// load instruction touches 16 contiguous cache lines (optimal), instead of
// the old row-per-thread pattern (64 scattered lines/instruction).
// Gallery norms are fused into the dot loop (q accumulator), so no extra
// workspace beyond the 384 partials is needed.
// ---------------------------------------------------------------------------
__global__ __launch_bounds__(256) void smoothap_main(
    const float* __restrict__ preds, const float* __restrict__ gallery,
    float* __restrict__ partials)
{
    __shared__ float s[BATCH];
    __shared__ float rk[GROUP];
    __shared__ float part[4][GROUP];

    const int i    = blockIdx.x;
    const int t    = threadIdx.x;
    const int wave = t >> 6;
    const int lane = t & 63;
    const int sub  = lane & 15;   // position within 16-lane cluster
    const int grp  = lane >> 4;   // which of the 4 rows this cluster serves

    // ---- p-hat into registers: lane holds dims {sub*4 + 64*c .. +3}, c=0..3
    const float* prow = preds + i * FEAT + sub * 4;
    float4 p0 = *(const float4*)(prow);
    float4 p1 = *(const float4*)(prow + 64);
    float4 p2 = *(const float4*)(prow + 128);
    float4 p3 = *(const float4*)(prow + 192);

    float ssq = p0.x * p0.x + p0.y * p0.y + p0.z * p0.z + p0.w * p0.w
              + p1.x * p1.x + p1.y * p1.y + p1.z * p1.z + p1.w * p1.w
              + p2.x * p2.x + p2.y * p2.y + p2.z * p2.z + p2.w * p2.w
              + p3.x * p3.x + p3.y * p3.y + p3.z * p3.z + p3.w * p3.w;
    // each 16-lane cluster spans the full row -> reduce within cluster
    ssq += __shfl_xor(ssq, 1, 64);
    ssq += __shfl_xor(ssq, 2, 64);
    ssq += __shfl_xor(ssq, 4, 64);
    ssq += __shfl_xor(ssq, 8, 64);
    const float pn = fmaxf(sqrtf(ssq), 1e-12f);
    p0.x /= pn; p0.y /= pn; p0.z /= pn; p0.w /= pn;
    p1.x /= pn; p1.y /= pn; p1.z /= pn; p1.w /= pn;
    p2.x /= pn; p2.y /= pn; p2.z /= pn; p2.w /= pn;
    p3.x /= pn; p3.y /= pn; p3.z /= pn; p3.w /= pn;

    // ---- sim row: wave w computes s[k] for k in [w*96, w*96+96), 4 rows/iter
    const int r_end = wave * 96 + 96;
    for (int r = wave * 96; r < r_end; r += 4) {
        const float* g = gallery + (r + grp) * FEAT + sub * 4;
        float4 a = *(const float4*)(g);
        float4 b = *(const float4*)(g + 64);
        float4 c = *(const float4*)(g + 128);
        float4 d = *(const float4*)(g + 192);
        float dot = p0.x * a.x + p0.y * a.y + p0.z * a.z + p0.w * a.w
                  + p1.x * b.x + p1.y * b.y + p1.z * b.z + p1.w * b.w
                  + p2.x * c.x + p2.y * c.y + p2.z * c.z + p2.w * c.w
                  + p3.x * d.x + p3.y * d.y + p3.z * d.z + p3.w * d.w;
        float q   = a.x * a.x + a.y * a.y + a.z * a.z + a.w * a.w
                  + b.x * b.x + b.y * b.y + b.z * b.z + b.w * b.w
                  + c.x * c.x + c.y * c.y + c.z * c.z + c.w * c.w
                  + d.x * d.x + d.y * d.y + d.z * d.z + d.w * d.w;
        dot += __shfl_xor(dot, 1, 64);  q += __shfl_xor(q, 1, 64);
        dot += __shfl_xor(dot, 2, 64);  q += __shfl_xor(q, 2, 64);
        dot += __shfl_xor(dot, 4, 64);  q += __shfl_xor(q, 4, 64);
        dot += __shfl_xor(dot, 8, 64);  q += __shfl_xor(q, 8, 64);
        if (sub == 0) s[r + grp] = dot / fmaxf(sqrtf(q), 1e-12f);
    }
    __syncthreads();

    const int base = (i >> 3) * GROUP;  // start of this id's diagonal block
    float sb[GROUP];
    #pragma unroll
    for (int b = 0; b < GROUP; b++) sb[b] = s[base + b];

    // ---- rk[b] = sum_k sigmoid_t(s[k] - s[base+b]) ----
    float acc8[GROUP];
    #pragma unroll
    for (int b = 0; b < GROUP; b++) acc8[b] = 0.0f;
    for (int k = t; k < BATCH; k += 256) {
        float sk = s[k];
        #pragma unroll
        for (int b = 0; b < GROUP; b++)
            acc8[b] += temp_sigmoid_from_diff(sk - sb[b]);
    }
    #pragma unroll
    for (int b = 0; b < GROUP; b++) {
        float v = acc8[b];
        #pragma unroll
        for (int m = 32; m >= 1; m >>= 1) v += __shfl_xor(v, m, 64);
        acc8[b] = v;
    }
    if ((t & 63) == 0) {
        #pragma unroll
        for (int b = 0; b < GROUP; b++) part[t >> 6][b] = acc8[b];
    }
    __syncthreads();
    if (t < GROUP) rk[t] = part[0][t] + part[1][t] + part[2][t] + part[3][t];
    __syncthreads();

    // ---- pos part on wave 0: lane = 8*b + c ----
    if (t < 64) {
        int b = t >> 3, c = t & 7;
        float v = temp_sigmoid_from_diff(s[base + c] - s[base + b]);
        v += __shfl_xor(v, 1, 64);
        v += __shfl_xor(v, 2, 64);
        v += __shfl_xor(v, 4, 64);   // lanes of group b hold pos_rk[b]
        float contrib = (c == 0) ? (v / rk[b]) : 0.0f;
        contrib += __shfl_xor(contrib, 8, 64);
        contrib += __shfl_xor(contrib, 16, 64);
        contrib += __shfl_xor(contrib, 32, 64);
        if (t == 0) partials[i] = contrib;   // unconditional write -> poison-safe
    }
}

// Single block: sum 384 partials, finalize.
__global__ __launch_bounds__(256) void smoothap_finalize(
    const float* __restrict__ partials, float* __restrict__ out)
{
    __shared__ float red4[4];
    const int t = threadIdx.x;
    float v = partials[t];
    if (t < BATCH - 256) v += partials[t + 256];
    #pragma unroll
    for (int m = 32; m >= 1; m >>= 1) v += __shfl_xor(v, m, 64);
    if ((t & 63) == 0) red4[t >> 6] = v;
    __syncthreads();
    if (t == 0)
        out[0] = 1.0f - (red4[0] + red4[1] + red4[2] + red4[3])
                        / (float)(GROUP * BATCH);
}

extern "C" void kernel_launch(void* const* d_in, const int* in_sizes, int n_in,
                              void* d_out, int out_size, void* d_ws, size_t ws_size,
                              hipStream_t stream) {
    const float* preds   = (const float*)d_in[0];
    const float* gallery = (const float*)d_in[1];
    float* out = (float*)d_out;
    float* partials = (float*)d_ws;   // 384 floats, fully overwritten every call

    smoothap_main<<<BATCH, 256, 0, stream>>>(preds, gallery, partials);
    smoothap_finalize<<<1, 256, 0, stream>>>(partials, out);
}